// Round 1
// baseline (456.644 us; speedup 1.0000x reference)
//
#include <hip/hip_runtime.h>
#include <cstdint>
#include <cstddef>

#define F_ALPHA 0.5f
#define THRESH  0.5f
#define EPS8    1e-8f
#define EPS7    1e-7f
#define MAXM    64
#define CCLS    21

// ---------------------------------------------------------------------------
// Kernel A: per-prior best GT (bt) + per-GT best prior (bp) matching.
// grid = (ceil(P/256), B), block = 256.
// dynamic LDS layout: float4 tb[M] | float tarea[M] | float ioubuf[M][257]
// (row stride 257 floats to break the 256-stride bank aliasing in the
//  per-GT reduce phase)
// ---------------------------------------------------------------------------
__global__ void match_kernel(const float4* __restrict__ dbox,
                             const float4* __restrict__ gt,
                             unsigned long long* __restrict__ bpkey,
                             unsigned char* __restrict__ match,
                             int P, int M)
{
    extern __shared__ float smem[];
    float4* tb    = (float4*)smem;                 // M float4, 16B aligned
    float*  tarea = (float*)(tb + M);              // M floats
    float*  ioubuf = tarea + M;                    // M * 257 floats

    const int t = threadIdx.x;
    const int b = blockIdx.y;
    const int p = blockIdx.x * 256 + t;

    if (t < M) {
        float4 g = gt[(size_t)b * M + t];
        tb[t] = g;
        tarea[t] = (g.z - g.x) * (g.w - g.y);
    }
    __syncthreads();

    const bool valid = (p < P);
    float4 d = valid ? dbox[p] : make_float4(0.f, 0.f, 0.f, 0.f);
    float darea = (d.z - d.x) * (d.w - d.y);

    float best = -1.0f;
    int bm = 0;
    for (int m = 0; m < M; m++) {
        float iou;
        if (valid) {
            float4 g = tb[m];
            float lx = fmaxf(d.x, g.x), ly = fmaxf(d.y, g.y);
            float rx = fminf(d.z, g.z), ry = fminf(d.w, g.w);
            float w = fmaxf(rx - lx, 0.f), h = fmaxf(ry - ly, 0.f);
            float inter = w * h;
            iou = inter / (darea + tarea[m] - inter);
        } else {
            iou = -1.0f;   // never wins
        }
        ioubuf[m * 257 + t] = iou;
        if (iou > best) { best = iou; bm = m; }   // strict > : first-index tie, matches jnp.argmax
    }
    if (valid) {
        unsigned char code = (unsigned char)((best >= THRESH ? 0x40 : 0) | bm);
        match[(size_t)b * P + p] = code;
    }
    __syncthreads();

    // per-GT argmax over this block's 256 priors: 5 partial scanners per row
    __shared__ float pval[MAXM * 5];
    __shared__ int   pidx[MAXM * 5];
    if (t < M * 5) {
        int row = t / 5, g = t % 5;
        float bv = -1.0f; int bj = 0;
        for (int j = g; j < 256; j += 5) {
            float v = ioubuf[row * 257 + j];
            if (v > bv) { bv = v; bj = j; }
        }
        pval[t] = bv; pidx[t] = bj;
    }
    __syncthreads();
    if (t < M) {
        float bv = -1.0f; int bj = 1 << 30;
        for (int g = 0; g < 5; g++) {
            float v = pval[t * 5 + g]; int j = pidx[t * 5 + g];
            if (v > bv || (v == bv && j < bj)) { bv = v; bj = j; }
        }
        unsigned pp = blockIdx.x * 256 + (unsigned)bj;
        // key: larger iou wins; tie -> smaller p (matches argmax over axis 0)
        unsigned long long key = ((unsigned long long)__float_as_uint(bv) << 32)
                               | (unsigned long long)(0xFFFFFFFFu - pp);
        atomicMax(&bpkey[(size_t)b * M + t], key);
    }
}

// ---------------------------------------------------------------------------
// Kernel B: force-match each GT's best prior. Sequential per batch (M=50),
// last-wins on duplicate priors (scatter-with-duplicates semantics).
// ---------------------------------------------------------------------------
__global__ void force_kernel(const unsigned long long* __restrict__ bpkey,
                             unsigned char* __restrict__ match,
                             int P, int M)
{
    int b = blockIdx.x;
    if (threadIdx.x == 0) {
        for (int j = 0; j < M; j++) {
            unsigned long long k = bpkey[(size_t)b * M + j];
            unsigned p = 0xFFFFFFFFu - (unsigned)(k & 0xFFFFFFFFull);
            match[(size_t)b * P + p] = (unsigned char)(0x80 | j);
        }
    }
}

// ---------------------------------------------------------------------------
// Kernel C: focal loss on every anchor + GIoU on positives.
// Accumulate (sum_loc + sum_focal) in double, num_pos in uint.
// ---------------------------------------------------------------------------
__global__ void loss_kernel(const float4* __restrict__ locp,
                            const float*  __restrict__ conf,
                            const float4* __restrict__ dbox,
                            const float4* __restrict__ gt,
                            const int*    __restrict__ gtl,
                            const unsigned char* __restrict__ match,
                            double* __restrict__ S,
                            unsigned int* __restrict__ NP,
                            int P, int M)
{
    __shared__ float4 tb[MAXM];
    __shared__ int    tl[MAXM];
    const int t = threadIdx.x;
    const int b = blockIdx.y;
    const int p = blockIdx.x * 256 + t;

    if (t < M) {
        tb[t] = gt[(size_t)b * M + t];
        tl[t] = gtl[(size_t)b * M + t];
    }
    __syncthreads();

    double acc = 0.0;
    int cnt = 0;
    if (p < P) {
        unsigned char code = match[(size_t)b * P + p];
        int  idx = code & 0x3F;
        bool pos = (code & 0xC0) != 0;
        int  lbl = pos ? tl[idx] : 0;

        // ---- focal loss ----
        const float* cp = conf + ((size_t)b * P + p) * CCLS;
        float x[CCLS];
        float mx = -1e30f;
        #pragma unroll
        for (int c = 0; c < CCLS; c++) { x[c] = cp[c]; mx = fmaxf(mx, x[c]); }
        float sum = 0.f;
        #pragma unroll
        for (int c = 0; c < CCLS; c++) sum += expf(x[c] - mx);
        float ce = (mx + logf(sum)) - x[lbl];
        float pt = expf(-ce);
        float om = 1.f - pt;
        float fl = F_ALPHA * om * sqrtf(om) * ce;   // (1-pt)^1.5 = om*sqrt(om)
        acc = (double)fl;

        // ---- GIoU for positives ----
        if (pos) {
            cnt = 1;
            float4 d = dbox[p];
            float dw = d.z - d.x, dh = d.w - d.y;
            float dcx = d.x + dw * 0.5f, dcy = d.y + dh * 0.5f;
            float4 g = tb[idx];
            float gw = g.z - g.x, gh = g.w - g.y;
            float gcx = g.x + gw * 0.5f, gcy = g.y + gh * 0.5f;
            // encode target vs anchor
            float ex = (gcx - dcx) / (dw + EPS8);
            float ey = (gcy - dcy) / (dh + EPS8);
            float ew = logf(gw / (dw + EPS8) + EPS8);
            float eh = logf(gh / (dh + EPS8) + EPS8);
            // decode target
            float tcx = ex * dw + dcx, tcy = ey * dh + dcy;
            float tw = expf(ew) * dw,  th = expf(eh) * dh;
            float t0 = tcx - tw * 0.5f, t1 = tcy - th * 0.5f;
            float t2 = tcx + tw * 0.5f, t3 = tcy + th * 0.5f;
            // decode prediction
            float4 l = locp[(size_t)b * P + p];
            float pcx = l.x * dw + dcx, pcy = l.y * dh + dcy;
            float pw = expf(l.z) * dw,  ph = expf(l.w) * dh;
            float q0 = pcx - pw * 0.5f, q1 = pcy - ph * 0.5f;
            float q2 = pcx + pw * 0.5f, q3 = pcy + ph * 0.5f;
            // giou
            float ix0 = fmaxf(q0, t0), iy0 = fmaxf(q1, t1);
            float ix1 = fminf(q2, t2), iy1 = fminf(q3, t3);
            float iw = fmaxf(ix1 - ix0, 0.f), ih = fmaxf(iy1 - iy0, 0.f);
            float inter = iw * ih;
            float pa = (q2 - q0) * (q3 - q1);
            float ta = (t2 - t0) * (t3 - t1);
            float uni = pa + ta - inter;
            float iou = inter / (uni + EPS7);
            float e0 = fminf(q0, t0), e1 = fminf(q1, t1);
            float e2 = fmaxf(q2, t2), e3 = fmaxf(q3, t3);
            float ewd = fmaxf(e2 - e0, 0.f), ehd = fmaxf(e3 - e1, 0.f);
            float encl = ewd * ehd;
            float giou = iou - (encl - uni) / (encl + EPS7);
            acc += (double)(1.f - giou);
        }
    }

    // block reduce (wave64 shuffle + LDS across 4 waves)
    for (int o = 32; o > 0; o >>= 1) {
        acc += __shfl_down(acc, o, 64);
        cnt += __shfl_down(cnt, o, 64);
    }
    __shared__ double sv[4];
    __shared__ int    sc[4];
    int w = t >> 6, lane = t & 63;
    if (lane == 0) { sv[w] = acc; sc[w] = cnt; }
    __syncthreads();
    if (t == 0) {
        double a = sv[0] + sv[1] + sv[2] + sv[3];
        int    c = sc[0] + sc[1] + sc[2] + sc[3];
        atomicAdd(S, a);
        if (c) atomicAdd(NP, (unsigned)c);
    }
}

__global__ void final_kernel(const double* __restrict__ S,
                             const unsigned int* __restrict__ NP,
                             float* __restrict__ out)
{
    unsigned n = *NP;
    out[0] = (n == 0) ? 0.0f : (float)(*S / (double)n);
}

// ---------------------------------------------------------------------------
extern "C" void kernel_launch(void* const* d_in, const int* in_sizes, int n_in,
                              void* d_out, int out_size, void* d_ws, size_t ws_size,
                              hipStream_t stream)
{
    const float* locp = (const float*)d_in[0];   // [B,P,4]
    const float* conf = (const float*)d_in[1];   // [B,P,C]
    const float* dbox = (const float*)d_in[2];   // [P,4]
    const float* gt   = (const float*)d_in[3];   // [B,M,4]
    const int*   gtl  = (const int*)d_in[4];     // [B,M]

    const int P  = in_sizes[2] / 4;
    const long long BP = (long long)in_sizes[0] / 4;
    const int B  = (int)(BP / P);
    const int M  = in_sizes[4] / B;

    // workspace layout: bpkey[B*M] u64 | double S | uint NP | pad | match[B*P] u8
    char* ws = (char*)d_ws;
    unsigned long long* bpkey = (unsigned long long*)ws;
    size_t off = ((size_t)B * M * 8 + 15) & ~(size_t)15;
    double*       Sacc = (double*)(ws + off);
    unsigned int* NP   = (unsigned int*)(ws + off + 8);
    unsigned char* match = (unsigned char*)(ws + off + 16);

    hipMemsetAsync(d_ws, 0, off + 16, stream);   // zero bpkey + accumulators

    const int nblk = (P + 255) / 256;
    dim3 grid(nblk, B);
    size_t shA = (size_t)M * sizeof(float4)      // tb
               + (size_t)M * sizeof(float)       // tarea
               + (size_t)M * 257 * sizeof(float);// ioubuf (padded stride)

    match_kernel<<<grid, 256, shA, stream>>>((const float4*)dbox, (const float4*)gt,
                                             bpkey, match, P, M);
    force_kernel<<<B, 64, 0, stream>>>(bpkey, match, P, M);
    loss_kernel<<<grid, 256, 0, stream>>>((const float4*)locp, conf, (const float4*)dbox,
                                          (const float4*)gt, gtl, match, Sacc, NP, P, M);
    final_kernel<<<1, 1, 0, stream>>>(Sacc, NP, (float*)d_out);
}